// Round 12
// baseline (188.528 us; speedup 1.0000x reference)
//
#include <hip/hip_runtime.h>

// ---------- common helpers ----------
typedef __bf16 bf16x8 __attribute__((ext_vector_type(8)));
typedef float  f32x4  __attribute__((ext_vector_type(4)));

#define LOG2E 1.44269504088896f

__device__ __forceinline__ float bfl(unsigned short s) {
    return __uint_as_float(((unsigned int)s) << 16);
}
__device__ __forceinline__ unsigned short f2bf(float f) {  // RNE
    unsigned int x = __float_as_uint(f);
    x += 0x7fffu + ((x >> 16) & 1u);
    return (unsigned short)(x >> 16);
}
__device__ __forceinline__ float fexp2(float x) { return __builtin_amdgcn_exp2f(x); }
__device__ __forceinline__ float fexp(float x)  { return __builtin_amdgcn_exp2f(x * LOG2E); }
__device__ __forceinline__ float frcp(float x)  { return __builtin_amdgcn_rcpf(x); }
__device__ __forceinline__ float silu_f(float x) {
    return x * frcp(1.f + fexp2(-x * LOG2E));
}
__device__ __forceinline__ void gl_lds(const unsigned short* g, unsigned short* l) {
    __builtin_amdgcn_global_load_lds(
        (__attribute__((address_space(1))) const void*)g,
        (__attribute__((address_space(3))) void*)l, 16, 0, 0);
}

// dims
#define BSZ   2
#define LSEQ  2048
#define DMODEL 1024
#define DI    2048
#define DS    16
#define NCH   32        // chunks
#define CL    64        // steps per chunk (LSEQ/NCH)

// ---------- f32 -> bf16 weight segments ----------
#define WI_N   4194304          // 2*DI*DMODEL
#define WXP_N  196608           // 96*DI
#define WDT_N  131072           // DI*64
#define WOUT_N 2097152          // DMODEL*DI
#define WSEG1  (WI_N)
#define WSEG2  (WI_N + WXP_N)
#define WSEG3  (WI_N + WXP_N + WDT_N)
#define WTOT   (WI_N + WXP_N + WDT_N + WOUT_N)   // 6,619,136
#define CVT_BLOCKS 3232                          // WTOT/8/256 (exact)

// ---------- fused LayerNorm (blocks 0..4095) + weight-convert (rest) --------
__global__ __launch_bounds__(256) void ln_cvt(
    const float* __restrict__ x,
    const float* __restrict__ g,
    const float* __restrict__ b,
    unsigned short* __restrict__ xn,
    const float* __restrict__ w0, const float* __restrict__ w1,
    const float* __restrict__ w2, const float* __restrict__ w3,
    unsigned short* __restrict__ dst)
{
    const int tid = threadIdx.x;
    if (blockIdx.x < BSZ * LSEQ) {
        const int row = blockIdx.x;
        const int lane = tid & 63, wv = tid >> 6;
        const float* xp = x + (size_t)row * DMODEL;

        float4 v = ((const float4*)xp)[tid];
        float s = v.x + v.y + v.z + v.w;
        float q = v.x*v.x + v.y*v.y + v.z*v.z + v.w*v.w;
        #pragma unroll
        for (int o = 32; o > 0; o >>= 1) {
            s += __shfl_down(s, o);
            q += __shfl_down(q, o);
        }
        __shared__ float ss[4], sq[4];
        if (lane == 0) { ss[wv] = s; sq[wv] = q; }
        __syncthreads();
        s = ss[0] + ss[1] + ss[2] + ss[3];
        q = sq[0] + sq[1] + sq[2] + sq[3];
        const float mu  = s * (1.f / DMODEL);
        const float var = q * (1.f / DMODEL) - mu * mu;
        const float rs  = rsqrtf(var + 1e-5f);

        float4 gv = ((const float4*)g)[tid];
        float4 bv = ((const float4*)b)[tid];
        ushort4 o;
        o.x = f2bf((v.x - mu) * rs * gv.x + bv.x);
        o.y = f2bf((v.y - mu) * rs * gv.y + bv.y);
        o.z = f2bf((v.z - mu) * rs * gv.z + bv.z);
        o.w = f2bf((v.w - mu) * rs * gv.w + bv.w);
        ((ushort4*)(xn + (size_t)row * DMODEL))[tid] = o;
    } else {
        const size_t e0 = ((size_t)(blockIdx.x - BSZ * LSEQ) * 256 + tid) * 8;
        if (e0 >= WTOT) return;
        const float* src;
        size_t off;
        if      (e0 < WSEG1) { src = w0; off = e0; }
        else if (e0 < WSEG2) { src = w1; off = e0 - WSEG1; }
        else if (e0 < WSEG3) { src = w2; off = e0 - WSEG2; }
        else                 { src = w3; off = e0 - WSEG3; }
        float4 a = *(const float4*)(src + off);
        float4 bb = *(const float4*)(src + off + 4);
        ushort4 lo, hi;
        lo.x = f2bf(a.x);  lo.y = f2bf(a.y);  lo.z = f2bf(a.z);  lo.w = f2bf(a.w);
        hi.x = f2bf(bb.x); hi.y = f2bf(bb.y); hi.z = f2bf(bb.z); hi.w = f2bf(bb.w);
        *(ushort4*)(dst + e0) = lo;
        *(ushort4*)(dst + e0 + 4) = hi;
    }
}

// ---------- 256x256 phase-interleaved pipelined GEMM (8 waves) --------------
// EPI 0: bf16 out via LDS-staged coalesced epilogue; z-half tiles (bn0>=DI)
//        store silu(v) so scan3 reads pre-gated z.
// EPI 3: f32 out + residual add
template<int EPI, int LOGM>
__global__ __launch_bounds__(512, 2) void gemm_pipe256(
    const unsigned short* __restrict__ A,
    const unsigned short* __restrict__ Bw,
    void* __restrict__ Cout,
    const void* __restrict__ aux0,
    int K, int ldc)
{
    __shared__ unsigned short As[2][256 * 64];
    __shared__ unsigned short Bs[2][256 * 64];
    const int tid  = threadIdx.x;
    const int lane = tid & 63;
    const int wid  = tid >> 6;
    const int wm   = (wid >> 2) * 128;   // 2 wave-rows
    const int wn   = (wid & 3) * 64;     // 4 wave-cols

    const int nwg = gridDim.x;
    const int id  = blockIdx.x;
    const int swz = (id & 7) * (nwg >> 3) + (id >> 3);
    const int bx  = swz & ((1 << LOGM) - 1);
    const int by  = swz >> LOGM;
    const size_t am0 = (size_t)bx * 256;
    const size_t bn0 = (size_t)by * 256;

    const int srow  = lane >> 3;                 // 0..7
    const int sslot = (lane & 7) ^ srow;         // pre-swizzled 16B slot
    const unsigned short* gA = A  + (am0 + wid * 8 + srow) * (size_t)K + sslot * 8;
    const unsigned short* gB = Bw + (bn0 + wid * 8 + srow) * (size_t)K + sslot * 8;

    const int NT = K >> 6;

#define STAGE256(buf, ko)                                                      \
    {   _Pragma("unroll")                                                      \
        for (int j = 0; j < 4; ++j)                                            \
            gl_lds(gA + (size_t)(j * 64) * K + (ko), &As[buf][(j * 64 + wid * 8) * 64]); \
        _Pragma("unroll")                                                      \
        for (int j = 0; j < 4; ++j)                                            \
            gl_lds(gB + (size_t)(j * 64) * K + (ko), &Bs[buf][(j * 64 + wid * 8) * 64]); }

    STAGE256(0, 0)
    STAGE256(1, 64)

    f32x4 acc[8][4];
    f32x4 z4 = {0.f, 0.f, 0.f, 0.f};
    #pragma unroll
    for (int i = 0; i < 8; ++i)
        #pragma unroll
        for (int j = 0; j < 4; ++j) acc[i][j] = z4;

    const int lr  = lane & 15;
    const int lq  = lane >> 4;       // 0..3
    const int key = lr & 7;          // swizzle key (row&7)

#define RD_A(dst, q)                                                           \
    _Pragma("unroll")                                                          \
    for (int i = 0; i < 2; ++i)                                                \
        _Pragma("unroll")                                                      \
        for (int ks = 0; ks < 2; ++ks)                                         \
            dst[i][ks] = *(const bf16x8*)&As[cur][(wm + ((q) * 2 + i) * 16 + lr) * 64 \
                                                  + (((ks * 4 + lq) ^ key) * 8)];

#define MFMA_Q(src, q)                                                         \
    _Pragma("unroll")                                                          \
    for (int i = 0; i < 2; ++i)                                                \
        _Pragma("unroll")                                                      \
        for (int fn = 0; fn < 4; ++fn) {                                       \
            acc[(q) * 2 + i][fn] = __builtin_amdgcn_mfma_f32_16x16x32_bf16(    \
                src[i][0], bfv[fn][0], acc[(q) * 2 + i][fn], 0, 0, 0);         \
            acc[(q) * 2 + i][fn] = __builtin_amdgcn_mfma_f32_16x16x32_bf16(    \
                src[i][1], bfv[fn][1], acc[(q) * 2 + i][fn], 0, 0, 0);         }

    for (int t = 0; t < NT; ++t) {
        const int cur = t & 1;
        if (t < NT - 1) asm volatile("s_waitcnt vmcnt(8)" ::: "memory");
        else            asm volatile("s_waitcnt vmcnt(0)" ::: "memory");
        __builtin_amdgcn_s_barrier();
        __builtin_amdgcn_sched_barrier(0);

        bf16x8 bfv[4][2], fA[2][2], fB[2][2];
        #pragma unroll
        for (int fn = 0; fn < 4; ++fn)
            #pragma unroll
            for (int ks = 0; ks < 2; ++ks)
                bfv[fn][ks] = *(const bf16x8*)&Bs[cur][(wn + fn * 16 + lr) * 64
                                                        + (((ks * 4 + lq) ^ key) * 8)];
        RD_A(fA, 0)
        asm volatile("s_waitcnt lgkmcnt(0)" ::: "memory");
        __builtin_amdgcn_sched_barrier(0);

        RD_A(fB, 1)
        __builtin_amdgcn_s_setprio(1);
        MFMA_Q(fA, 0)
        __builtin_amdgcn_s_setprio(0);
        asm volatile("s_waitcnt lgkmcnt(0)" ::: "memory");
        __builtin_amdgcn_sched_barrier(0);

        RD_A(fA, 2)
        __builtin_amdgcn_s_setprio(1);
        MFMA_Q(fB, 1)
        __builtin_amdgcn_s_setprio(0);
        asm volatile("s_waitcnt lgkmcnt(0)" ::: "memory");
        __builtin_amdgcn_sched_barrier(0);

        RD_A(fB, 3)
        __builtin_amdgcn_s_setprio(1);
        MFMA_Q(fA, 2)
        __builtin_amdgcn_s_setprio(0);
        asm volatile("s_waitcnt lgkmcnt(0)" ::: "memory");
        __builtin_amdgcn_sched_barrier(0);

        __builtin_amdgcn_s_barrier();
        if (t + 2 < NT) {
            STAGE256(cur, (size_t)(t + 2) * 64)
        }
        __builtin_amdgcn_s_setprio(1);
        MFMA_Q(fB, 3)
        __builtin_amdgcn_s_setprio(0);
    }
#undef RD_A
#undef MFMA_Q
#undef STAGE256

    // all waves done reading LDS before epilogue reuses As
    asm volatile("s_waitcnt vmcnt(0) lgkmcnt(0)" ::: "memory");
    __builtin_amdgcn_s_barrier();

    const int er = lq * 4;
    const int ec = lr;
    if constexpr (EPI == 0) {
        // LDS-staged coalesced C-write: per-wave [16][88] bf16 region in As
        const bool zhalf = (bn0 >= (size_t)DI);   // tile in z-half -> pre-gate
        unsigned short* cw = &As[0][0] + wid * (16 * 88);
        const int rl  = lane >> 2;        // 0..15
        const int c8l = lane & 3;         // 0..3
        unsigned short* cbase = (unsigned short*)Cout;
        #pragma unroll
        for (int fm = 0; fm < 8; ++fm) {
            #pragma unroll
            for (int fn = 0; fn < 4; ++fn)
                #pragma unroll
                for (int r = 0; r < 4; ++r) {
                    float v = acc[fm][fn][r];
                    if (zhalf) v = silu_f(v);
                    cw[(er + r) * 88 + fn * 16 + ec] = f2bf(v);
                }
            #pragma unroll
            for (int u = 0; u < 2; ++u) {
                const int c8 = c8l + 4 * u;
                bf16x8 v = *(const bf16x8*)&cw[rl * 88 + c8 * 8];
                const size_t row = am0 + wm + fm * 16 + rl;
                const size_t col = bn0 + wn + c8 * 8;
                *(bf16x8*)(cbase + row * (size_t)ldc + col) = v;
            }
        }
    } else {
        #pragma unroll
        for (int fm = 0; fm < 8; ++fm) {
            #pragma unroll
            for (int fn = 0; fn < 4; ++fn) {
                const size_t col = bn0 + wn + fn * 16 + ec;
                #pragma unroll
                for (int r = 0; r < 4; ++r) {
                    const size_t row = am0 + wm + fm * 16 + er + r;
                    float t2 = acc[fm][fn][r] + ((const float*)aux0)[row * ldc + col];
                    ((float*)Cout)[row * ldc + col] = t2;
                }
            }
        }
    }
}

// ---------- 128x128 phase-interleaved pipelined GEMM (8 waves) --------------
template<int EPI, int LOGNB>
__global__ __launch_bounds__(512, 2) void gemm_pipe128(
    const unsigned short* __restrict__ A,
    const unsigned short* __restrict__ Bw,
    void* __restrict__ Cout,
    const void* __restrict__ aux0,
    int K, int ldc)
{
    __shared__ unsigned short As[2][128 * 64];
    __shared__ unsigned short Bs[2][128 * 64];
    const int tid  = threadIdx.x;
    const int lane = tid & 63;
    const int wid  = tid >> 6;
    const int wm   = (wid >> 2) * 64;    // 2 wave-rows
    const int wn   = (wid & 3) * 32;     // 4 wave-cols

    const int nwg = gridDim.x;
    const int id  = blockIdx.x;
    const int swz = (id & 7) * (nwg >> 3) + (id >> 3);
    const int bn_i = swz & ((1 << LOGNB) - 1);
    const int bm_i = swz >> LOGNB;
    const size_t am0 = (size_t)bm_i * 128;
    const size_t bn0 = (size_t)bn_i * 128;

    const int srow  = lane >> 3;                 // 0..7
    const int sslot = (lane & 7) ^ srow;         // pre-swizzled 16B slot
    const unsigned short* gA = A  + (am0 + wid * 16 + srow) * (size_t)K + sslot * 8;
    const unsigned short* gB = Bw + (bn0 + wid * 16 + srow) * (size_t)K + sslot * 8;

    const int NT = K >> 6;

#define STAGE128(buf, ko)                                                      \
    {   _Pragma("unroll")                                                      \
        for (int j = 0; j < 2; ++j)                                            \
            gl_lds(gA + (size_t)(j * 8) * K + (ko), &As[buf][(wid * 16 + j * 8) * 64]); \
        _Pragma("unroll")                                                      \
        for (int j = 0; j < 2; ++j)                                            \
            gl_lds(gB + (size_t)(j * 8) * K + (ko), &Bs[buf][(wid * 16 + j * 8) * 64]); }

    STAGE128(0, 0)
    STAGE128(1, 64)

    f32x4 acc[4][2];
    f32x4 z4 = {0.f, 0.f, 0.f, 0.f};
    #pragma unroll
    for (int i = 0; i < 4; ++i) { acc[i][0] = z4; acc[i][1] = z4; }

    const int lr  = lane & 15;
    const int lq  = lane >> 4;       // 0..3
    const int key = lr & 7;          // swizzle key (row&7)

#define RD_A128(dst, h)                                                        \
    _Pragma("unroll")                                                          \
    for (int i = 0; i < 2; ++i)                                                \
        _Pragma("unroll")                                                      \
        for (int ks = 0; ks < 2; ++ks)                                         \
            dst[i][ks] = *(const bf16x8*)&As[cur][(wm + ((h) * 2 + i) * 16 + lr) * 64 \
                                                  + (((ks * 4 + lq) ^ key) * 8)];

#define MFMA_H(src, h)                                                         \
    _Pragma("unroll")                                                          \
    for (int i = 0; i < 2; ++i)                                                \
        _Pragma("unroll")                                                      \
        for (int fn = 0; fn < 2; ++fn) {                                       \
            acc[(h) * 2 + i][fn] = __builtin_amdgcn_mfma_f32_16x16x32_bf16(    \
                src[i][0], bfv[fn][0], acc[(h) * 2 + i][fn], 0, 0, 0);         \
            acc[(h) * 2 + i][fn] = __builtin_amdgcn_mfma_f32_16x16x32_bf16(    \
                src[i][1], bfv[fn][1], acc[(h) * 2 + i][fn], 0, 0, 0);         }

    for (int t = 0; t < NT; ++t) {
        const int cur = t & 1;
        if (t < NT - 1) asm volatile("s_waitcnt vmcnt(4)" ::: "memory");
        else            asm volatile("s_waitcnt vmcnt(0)" ::: "memory");
        __builtin_amdgcn_s_barrier();
        __builtin_amdgcn_sched_barrier(0);

        bf16x8 bfv[2][2], fA[2][2], fB[2][2];
        #pragma unroll
        for (int fn = 0; fn < 2; ++fn)
            #pragma unroll
            for (int ks = 0; ks < 2; ++ks)
                bfv[fn][ks] = *(const bf16x8*)&Bs[cur][(wn + fn * 16 + lr) * 64
                                                        + (((ks * 4 + lq) ^ key) * 8)];
        RD_A128(fA, 0)
        asm volatile("s_waitcnt lgkmcnt(0)" ::: "memory");
        __builtin_amdgcn_sched_barrier(0);

        RD_A128(fB, 1)
        __builtin_amdgcn_s_setprio(1);
        MFMA_H(fA, 0)
        __builtin_amdgcn_s_setprio(0);
        asm volatile("s_waitcnt lgkmcnt(0)" ::: "memory");
        __builtin_amdgcn_sched_barrier(0);

        __builtin_amdgcn_s_barrier();     // release buf[cur]
        if (t + 2 < NT) {
            STAGE128(cur, (size_t)(t + 2) * 64)
        }
        __builtin_amdgcn_s_setprio(1);
        MFMA_H(fB, 1)
        __builtin_amdgcn_s_setprio(0);
    }
#undef RD_A128
#undef MFMA_H
#undef STAGE128

    const int er = lq * 4;
    const int ec = lr;
    #pragma unroll
    for (int fm = 0; fm < 4; ++fm) {
        #pragma unroll
        for (int fn = 0; fn < 2; ++fn) {
            const size_t col = bn0 + wn + fn * 16 + ec;
            #pragma unroll
            for (int r = 0; r < 4; ++r) {
                const size_t row = am0 + wm + fm * 16 + er + r;
                float v = acc[fm][fn][r];
                if constexpr (EPI == 0) {
                    ((unsigned short*)Cout)[row * ldc + col] = f2bf(v);
                } else {
                    float t2 = v + ((const float*)aux0)[row * ldc + col];
                    ((float*)Cout)[row * ldc + col] = t2;
                }
            }
        }
    }
}

// ---------- tiled GEMM, global_load_lds staging (m97 structure) ----------
template<int BM, int BN, int EPI, int LOG_NBXM>
__global__ __launch_bounds__(256) void gemm_lds(
    const unsigned short* __restrict__ A,
    const unsigned short* __restrict__ Bw,
    void* __restrict__ Cout,
    const void* __restrict__ aux0,
    int K, int ldc)
{
    constexpr int FM = BM / 32;
    constexpr int FN = BN / 32;
    __shared__ unsigned short As[BM * 64];
    __shared__ unsigned short Bs[BN * 64];
    const int tid  = threadIdx.x;
    const int lane = tid & 63;
    const int wv   = tid >> 6;
    const int wm   = (wv >> 1) * (BM / 2);
    const int wn   = (wv & 1)  * (BN / 2);

    const int nwg = gridDim.x;
    const int id  = blockIdx.x;
    const int swz = (id & 7) * (nwg >> 3) + (id >> 3);
    const int bx  = swz & ((1 << LOG_NBXM) - 1);
    const int by  = swz >> LOG_NBXM;

    f32x4 acc[FM][FN];
    f32x4 z4 = {0.f, 0.f, 0.f, 0.f};
    #pragma unroll
    for (int i = 0; i < FM; ++i)
        #pragma unroll
        for (int j = 0; j < FN; ++j) acc[i][j] = z4;

    const size_t am0 = (size_t)bx * BM;
    const size_t bn0 = (size_t)by * BN;
    const int srow  = lane >> 3;          // 0..7
    const int scol  = (lane & 7) * 8;     // 0..56

    for (int k0 = 0; k0 < K; k0 += 64) {
        __syncthreads();
        #pragma unroll
        for (int i = 0; i < BM / 32; ++i) {
            const int rb = (wv * (BM / 32) + i) * 8;
            gl_lds(&A[(am0 + rb + srow) * (size_t)K + k0 + scol], &As[rb * 64]);
        }
        #pragma unroll
        for (int i = 0; i < BN / 32; ++i) {
            const int rb = (wv * (BN / 32) + i) * 8;
            gl_lds(&Bw[(bn0 + rb + srow) * (size_t)K + k0 + scol], &Bs[rb * 64]);
        }
        __syncthreads();
        const int lr = lane & 15, lk = (lane >> 4) * 8;
        #pragma unroll
        for (int ks = 0; ks < 2; ++ks) {
            bf16x8 af[FM], bfv[FN];
            #pragma unroll
            for (int fm = 0; fm < FM; ++fm)
                af[fm] = *(const bf16x8*)&As[(wm + fm * 16 + lr) * 64 + ks * 32 + lk];
            #pragma unroll
            for (int fn = 0; fn < FN; ++fn)
                bfv[fn] = *(const bf16x8*)&Bs[(wn + fn * 16 + lr) * 64 + ks * 32 + lk];
            #pragma unroll
            for (int fm = 0; fm < FM; ++fm)
                #pragma unroll
                for (int fn = 0; fn < FN; ++fn)
                    acc[fm][fn] = __builtin_amdgcn_mfma_f32_16x16x32_bf16(
                        af[fm], bfv[fn], acc[fm][fn], 0, 0, 0);
        }
    }

    const int er = (lane >> 4) * 4;
    const int ec = lane & 15;
    #pragma unroll
    for (int fm = 0; fm < FM; ++fm) {
        #pragma unroll
        for (int fn = 0; fn < FN; ++fn) {
            const size_t col = bn0 + wn + fn * 16 + ec;
            #pragma unroll
            for (int r = 0; r < 4; ++r) {
                const size_t row = am0 + wm + fm * 16 + er + r;
                float v = acc[fm][fn][r];
                if constexpr (EPI == 0) {
                    ((unsigned short*)Cout)[row * ldc + col] = f2bf(v);
                } else if constexpr (EPI == 2) {
                    float t = v + ((const float*)aux0)[col];
                    float e = fexp2(t * LOG2E);
                    float sp = 0.69314718056f * __builtin_amdgcn_logf(1.f + e);
                    if (t > 20.f) sp = t;
                    ((unsigned short*)Cout)[row * ldc + col] = f2bf(sp);
                } else {
                    float t = v + ((const float*)aux0)[row * ldc + col];
                    ((float*)Cout)[row * ldc + col] = t;
                }
            }
        }
    }
}

// ---------- GEMM4 split-K ----------
__global__ __launch_bounds__(256) void gemm4_splitk(
    const unsigned short* __restrict__ A,    // (4096, 2048) bf16
    const unsigned short* __restrict__ Bw,   // (96, 2048) bf16
    float* __restrict__ Cpart)               // (8, 4096, 96) f32
{
    constexpr int LDP = 72;
    __shared__ unsigned short As[64 * LDP];
    __shared__ unsigned short Bs[96 * LDP];
    const int tid  = threadIdx.x;
    const int lane = tid & 63;
    const int wv   = tid >> 6;
    const int wm   = (wv >> 1) * 32;
    const int wn   = (wv & 1)  * 48;

    f32x4 acc[2][3];
    f32x4 z4 = {0.f, 0.f, 0.f, 0.f};
    #pragma unroll
    for (int i = 0; i < 2; ++i)
        #pragma unroll
        for (int j = 0; j < 3; ++j) acc[i][j] = z4;

    const size_t am0 = (size_t)blockIdx.x * 64;
    const int kz = blockIdx.y;
    const int kbeg = kz * 256;
    const int r0 = tid >> 3;
    const int c0 = (tid & 7) * 8;

    for (int k0 = kbeg; k0 < kbeg + 256; k0 += 64) {
        __syncthreads();
        #pragma unroll
        for (int p = 0; p < 2; ++p) {
            int r = r0 + p * 32;
            *(uint4*)&As[r * LDP + c0] = *(const uint4*)&A[(am0 + r) * (size_t)2048 + k0 + c0];
        }
        #pragma unroll
        for (int p = 0; p < 3; ++p) {
            int r = r0 + p * 32;
            *(uint4*)&Bs[r * LDP + c0] = *(const uint4*)&Bw[(size_t)r * 2048 + k0 + c0];
        }
        __syncthreads();
        const int lr = lane & 15, lk = (lane >> 4) * 8;
        #pragma unroll
        for (int ks = 0; ks < 2; ++ks) {
            bf16x8 af[2], bfv[3];
            #pragma unroll
            for (int fm = 0; fm < 2; ++fm)
                af[fm] = *(const bf16x8*)&As[(wm + fm * 16 + lr) * LDP + ks * 32 + lk];
            #pragma unroll
            for (int fn = 0; fn < 3; ++fn)
                bfv[fn] = *(const bf16x8*)&Bs[(wn + fn * 16 + lr) * LDP + ks * 32 + lk];
            #pragma unroll
            for (int fm = 0; fm < 2; ++fm)
                #pragma unroll
                for (int fn = 0; fn < 3; ++fn)
                    acc[fm][fn] = __builtin_amdgcn_mfma_f32_16x16x32_bf16(
                        af[fm], bfv[fn], acc[fm][fn], 0, 0, 0);
        }
    }

    const int er = (lane >> 4) * 4;
    const int ec = lane & 15;
    float* out = Cpart + (size_t)kz * 4096 * 96;
    #pragma unroll
    for (int fm = 0; fm < 2; ++fm) {
        #pragma unroll
        for (int fn = 0; fn < 3; ++fn) {
            const int col = wn + fn * 16 + ec;
            #pragma unroll
            for (int r = 0; r < 4; ++r) {
                const size_t row = am0 + wm + fm * 16 + er + r;
                out[row * 96 + col] = acc[fm][fn][r];
            }
        }
    }
}

// ---------- reduce split-K partials -> x_dbl f32 + dtlow bf16 ----------
__global__ __launch_bounds__(256) void reduce_xdbl(
    const float* __restrict__ Cpart,     // (8, 4096, 96)
    float* __restrict__ x_dbl,           // (4096, 96)
    unsigned short* __restrict__ dtlow)  // (4096, 64) bf16
{
    const int e = blockIdx.x * 256 + threadIdx.x;   // < 393216
    float s = 0.f;
    #pragma unroll
    for (int kz = 0; kz < 8; ++kz) s += Cpart[(size_t)kz * 393216 + e];
    x_dbl[e] = s;
    const int row = e / 96, col = e - row * 96;
    if (col < 64) dtlow[row * 64 + col] = f2bf(s);
}

// ---------- causal depthwise conv (window 4) + bias + SiLU ----------
__global__ __launch_bounds__(256) void conv_silu(
    const unsigned short* __restrict__ xz,     // (B*L, 2*DI) bf16, u = cols [0,DI)
    const float* __restrict__ convw,           // (DI,4) f32
    const float* __restrict__ convb,           // (DI,) f32
    unsigned short* __restrict__ u_c)          // (B*L, DI) bf16
{
    const size_t i = (size_t)blockIdx.x * 256 + threadIdx.x;
    if (i >= (size_t)BSZ * LSEQ * DI) return;
    const int d = (int)(i & (DI - 1));
    const size_t bl = i >> 11;            // b*L + l
    const int l = (int)(bl & (LSEQ - 1));
    const int b = (int)(bl >> 11);

    float4 wv = *(const float4*)&convw[d * 4];
    float acc = convb[d];
    const size_t rowbase = (size_t)(b * LSEQ) * (2 * DI) + d;
    if (l >= 3) acc += bfl(xz[rowbase + (size_t)(l - 3) * (2 * DI)]) * wv.x;
    if (l >= 2) acc += bfl(xz[rowbase + (size_t)(l - 2) * (2 * DI)]) * wv.y;
    if (l >= 1) acc += bfl(xz[rowbase + (size_t)(l - 1) * (2 * DI)]) * wv.z;
    acc += bfl(xz[rowbase + (size_t)l * (2 * DI)]) * wv.w;
    u_c[i] = f2bf(silu_f(acc));
}

// ---------- A-row load: An2[n] = -exp(A_log[d][n]) * log2(e); fast = S4D ----------
__device__ __forceinline__ bool load_A(const float* __restrict__ A_log, int d, float* An2) {
    bool fast = true;
    #pragma unroll
    for (int i = 0; i < 4; ++i) {
        float4 a = *(const float4*)&A_log[(size_t)d * DS + i * 4];
        float e0 = fexp(a.x), e1 = fexp(a.y), e2 = fexp(a.z), e3 = fexp(a.w);
        fast = fast && fabsf(e0 - (4*i+1)) < 1e-3f * (4*i+1)
                    && fabsf(e1 - (4*i+2)) < 1e-3f * (4*i+2)
                    && fabsf(e2 - (4*i+3)) < 1e-3f * (4*i+3)
                    && fabsf(e3 - (4*i+4)) < 1e-3f * (4*i+4);
        An2[4*i+0] = -e0 * LOG2E; An2[4*i+1] = -e1 * LOG2E;
        An2[4*i+2] = -e2 * LOG2E; An2[4*i+3] = -e3 * LOG2E;
    }
    return fast;
}

// ---------- selective scan, pass 1: per-chunk local scan (h_in = 0) ----------
__global__ __launch_bounds__(256) void scan1(
    const unsigned short* __restrict__ dt,  // (B*L, DI) bf16
    const unsigned short* __restrict__ u_c, // (B*L, DI) bf16
    const float* __restrict__ x_dbl,        // (B*L, 96) f32; B = cols 64..79
    const float* __restrict__ A_log,        // (DI,16) f32
    float* __restrict__ chunk_h,            // [b][c][d][16] f32
    float* __restrict__ Ssum)               // [b][c][d] f32
{
    const int d = blockIdx.x * 256 + threadIdx.x;
    const int b = blockIdx.y, c = blockIdx.z;
    const int tid = threadIdx.x;

    __shared__ float sB[CL][DS];
    {
        int s = tid >> 2, j = (tid & 3) * 4;
        *(float4*)&sB[s][j] =
            *(const float4*)&x_dbl[(size_t)(b * LSEQ + c * CL + s) * 96 + 64 + j];
    }

    float An2[DS];
    const bool fast = load_A(A_log, d, An2);
    __syncthreads();

    float h[DS];
    #pragma unroll
    for (int n = 0; n < DS; ++n) h[n] = 0.f;
    float S = 0.f;
    const size_t base = (size_t)(b * LSEQ + c * CL) * DI + d;
    if (fast) {
        for (int s = 0; s < CL; ++s) {
            float dtt = bfl(dt[base + (size_t)s * DI]);
            float ut  = bfl(u_c[base + (size_t)s * DI]);
            S += dtt;
            float dtu = dtt * ut;
            float e1 = fexp2(-dtt * LOG2E);   // exp(-dt); dA[n] = e1^(n+1)
            float p = 1.f;
            #pragma unroll
            for (int n = 0; n < DS; ++n) {
                p *= e1;
                h[n] = p * h[n] + dtu * sB[s][n];
            }
        }
    } else {
        for (int s = 0; s < CL; ++s) {
            float dtt = bfl(dt[base + (size_t)s * DI]);
            float ut  = bfl(u_c[base + (size_t)s * DI]);
            S += dtt;
            float dtu = dtt * ut;
            #pragma unroll
            for (int n = 0; n < DS; ++n) {
                float dA = fexp2(dtt * An2[n]);
                h[n] = dA * h[n] + dtu * sB[s][n];
            }
        }
    }
    const size_t co = ((size_t)((b * NCH + c) * DI) + d) * DS;
    #pragma unroll
    for (int n = 0; n < DS; ++n) chunk_h[co + n] = h[n];
    Ssum[(size_t)(b * NCH + c) * DI + d] = S;
}

// ---------- scan pass 2: combine chunks; overwrite chunk_h with per-chunk h_in ----------
__global__ __launch_bounds__(256) void scan2(
    float* __restrict__ chunk_h,
    const float* __restrict__ Ssum,
    const float* __restrict__ A_log)
{
    const int gid = blockIdx.x * 256 + threadIdx.x;   // (b,d,n)
    const int b = gid >> 15;
    const int rem = gid & 32767;
    const int d = rem >> 4;
    const int n = rem & 15;
    const float A2 = -fexp(A_log[(size_t)d * DS + n]) * LOG2E;
    float H = 0.f;
    for (int c = 0; c < NCH; ++c) {
        const size_t idx = ((size_t)((b * NCH + c) * DI) + d) * DS + n;
        float hl = chunk_h[idx];
        float S  = Ssum[(size_t)(b * NCH + c) * DI + d];
        chunk_h[idx] = H;                 // start state for chunk c
        H = fexp2(A2 * S) * H + hl;
    }
}

// ---------- scan pass 3: full scan with h_in + y = (h.C + D*u) * silu(z) ----------
// NOTE: xz z-half now holds PRE-GATED silu(z) (applied in gemm_pipe256 epilogue)
__global__ __launch_bounds__(256) void scan3(
    const unsigned short* __restrict__ dt,
    const unsigned short* __restrict__ u_c,
    const float* __restrict__ x_dbl,          // B = 64..79, C = 80..95
    const float* __restrict__ A_log,
    const float* __restrict__ Hstart,
    const float* __restrict__ Dvec,           // (DI,) f32
    const unsigned short* __restrict__ xz,    // silu(z) = cols [DI, 2*DI) bf16
    unsigned short* __restrict__ yb)          // (B*L, DI) bf16
{
    const int d = blockIdx.x * 256 + threadIdx.x;
    const int b = blockIdx.y, c = blockIdx.z;
    const int tid = threadIdx.x;

    __shared__ float sBC[CL][32];
    {
        int s = tid >> 2, j = (tid & 3) * 8;
        *(float4*)&sBC[s][j] =
            *(const float4*)&x_dbl[(size_t)(b * LSEQ + c * CL + s) * 96 + 64 + j];
        *(float4*)&sBC[s][j + 4] =
            *(const float4*)&x_dbl[(size_t)(b * LSEQ + c * CL + s) * 96 + 64 + j + 4];
    }

    float An2[DS];
    const bool fast = load_A(A_log, d, An2);
    const float Dd = Dvec[d];
    float h[DS];
    const size_t co = ((size_t)((b * NCH + c) * DI) + d) * DS;
    #pragma unroll
    for (int n = 0; n < DS; ++n) h[n] = Hstart[co + n];
    __syncthreads();

    const size_t base  = (size_t)(b * LSEQ + c * CL) * DI + d;
    const size_t zbase = (size_t)(b * LSEQ + c * CL) * (2 * DI) + DI + d;
    if (fast) {
        for (int s = 0; s < CL; ++s) {
            float dtt = bfl(dt[base + (size_t)s * DI]);
            float ut  = bfl(u_c[base + (size_t)s * DI]);
            float dtu = dtt * ut;
            float e1 = fexp2(-dtt * LOG2E);
            float p = 1.f;
            float a0 = 0.f, a1 = 0.f;
            #pragma unroll
            for (int n = 0; n < DS; ++n) {
                p *= e1;
                h[n] = p * h[n] + dtu * sBC[s][n];
                if (n & 1) a1 += h[n] * sBC[s][16 + n];
                else       a0 += h[n] * sBC[s][16 + n];
            }
            float y = a0 + a1 + Dd * ut;
            float zs = bfl(xz[zbase + (size_t)s * (2 * DI)]);   // pre-gated silu(z)
            yb[base + (size_t)s * DI] = f2bf(y * zs);
        }
    } else {
        for (int s = 0; s < CL; ++s) {
            float dtt = bfl(dt[base + (size_t)s * DI]);
            float ut  = bfl(u_c[base + (size_t)s * DI]);
            float dtu = dtt * ut;
            float a0 = 0.f, a1 = 0.f;
            #pragma unroll
            for (int n = 0; n < DS; ++n) {
                float dA = fexp2(dtt * An2[n]);
                h[n] = dA * h[n] + dtu * sBC[s][n];
                if (n & 1) a1 += h[n] * sBC[s][16 + n];
                else       a0 += h[n] * sBC[s][16 + n];
            }
            float y = a0 + a1 + Dd * ut;
            float zs = bfl(xz[zbase + (size_t)s * (2 * DI)]);
            yb[base + (size_t)s * DI] = f2bf(y * zs);
        }
    }
}

// ---------- host launcher ----------
extern "C" void kernel_launch(void* const* d_in, const int* in_sizes, int n_in,
                              void* d_out, int out_size, void* d_ws, size_t ws_size,
                              hipStream_t stream) {
    const float* x      = (const float*)d_in[0];
    const float* ln_g   = (const float*)d_in[1];
    const float* ln_b   = (const float*)d_in[2];
    const float* W_in   = (const float*)d_in[3];
    const float* conv_w = (const float*)d_in[4];
    const float* conv_b = (const float*)d_in[5];
    const float* W_xp   = (const float*)d_in[6];
    const float* W_dt   = (const float*)d_in[7];
    const float* b_dt   = (const float*)d_in[8];
    const float* A_log  = (const float*)d_in[9];
    const float* Dv     = (const float*)d_in[10];
    const float* W_out  = (const float*)d_in[11];
    float* out = (float*)d_out;

    char* w = (char*)d_ws;
    unsigned short* xn     = (unsigned short*)(w + 0);           //  8,388,608
    unsigned short* xz     = (unsigned short*)(w + 8388608);     // 33,554,432
    unsigned short* u_c    = (unsigned short*)(w + 41943040);    // 16,777,216
    float*          x_dbl  = (float*)         (w + 58720256);    //  1,572,864
    unsigned short* dtlow  = (unsigned short*)(w + 60293120);    //    524,288
    unsigned short* dtb    = (unsigned short*)(w + 60817408);    // 16,777,216 (bf16)
    float*          chunkh = (float*)         (w + 77594624);    //  8,388,608 (NCH=32)
    float*          Ssum   = (float*)         (w + 94371840);    //    524,288
    unsigned short* yb     = (unsigned short*)(w + 95420416);    // 16,777,216
    unsigned short* wbf    = (unsigned short*)(w + 112197632);   // 13,238,272
    float*          Cpart  = (float*)         (w + 125435904);   // 12,582,912 (end 138,018,816)
    unsigned short* Wi_bf   = wbf;
    unsigned short* Wxp_bf  = wbf + WSEG1;
    unsigned short* Wdt_bf  = wbf + WSEG2;
    unsigned short* Wout_bf = wbf + WSEG3;
    (void)in_sizes; (void)n_in; (void)out_size; (void)ws_size;

    const int MROWS = BSZ * LSEQ;  // 4096

    // 0+1. fused LayerNorm (blocks 0..4095) + weight f32->bf16 (rest)
    ln_cvt<<<MROWS + CVT_BLOCKS, 256, 0, stream>>>(
        x, ln_g, ln_b, xn, W_in, W_xp, W_dt, W_out, wbf);
    // 2. xz = xn @ W_in^T  (4096x1024 @ 1024x4096) -> bf16; z-half pre-gated
    gemm_pipe256<0, 4><<<256, 512, 0, stream>>>(
        xn, Wi_bf, xz, nullptr, DMODEL, 2 * DI);
    // 3. causal conv + SiLU -> bf16 (reads u-half only; unaffected by pre-gate)
    conv_silu<<<(MROWS * DI) / 256, 256, 0, stream>>>(xz, conv_w, conv_b, u_c);
    // 4. x_dbl = u_c @ W_xp^T  (4096x2048 @ 2048x96), split-K + reduce
    gemm4_splitk<<<dim3(64, 8), 256, 0, stream>>>(u_c, Wxp_bf, Cpart);
    reduce_xdbl<<<(MROWS * 96) / 256, 256, 0, stream>>>(Cpart, x_dbl, dtlow);
    // 5. dt = softplus(dtlow @ W_dt^T + b_dt)  (4096x64 @ 64x2048) -> bf16
    gemm_lds<128, 64, 2, 5><<<1024, 256, 0, stream>>>(
        dtlow, Wdt_bf, dtb, b_dt, 64, DI);
    // 6-8. chunked selective scan (NCH=32, CL=64) -> yb bf16
    scan1<<<dim3(DI / 256, BSZ, NCH), 256, 0, stream>>>(
        dtb, u_c, x_dbl, A_log, chunkh, Ssum);
    scan2<<<(BSZ * DI * DS) / 256, 256, 0, stream>>>(chunkh, Ssum, A_log);
    scan3<<<dim3(DI / 256, BSZ, NCH), 256, 0, stream>>>(
        dtb, u_c, x_dbl, A_log, chunkh, Dv, xz, yb);
    // 9. out = yb @ W_out^T + x  (4096x2048 @ 2048x1024) -> f32
    gemm_pipe128<3, 3><<<256, 512, 0, stream>>>(
        yb, Wout_bf, out, x, DI, DMODEL);
}

// Round 13
// 179.953 us; speedup vs baseline: 1.0477x; 1.0477x over previous
//
#include <hip/hip_runtime.h>

// ---------- common helpers ----------
typedef __bf16 bf16x8 __attribute__((ext_vector_type(8)));
typedef float  f32x4  __attribute__((ext_vector_type(4)));

#define LOG2E 1.44269504088896f

__device__ __forceinline__ float bfl(unsigned short s) {
    return __uint_as_float(((unsigned int)s) << 16);
}
__device__ __forceinline__ unsigned short f2bf(float f) {  // RNE
    unsigned int x = __float_as_uint(f);
    x += 0x7fffu + ((x >> 16) & 1u);
    return (unsigned short)(x >> 16);
}
__device__ __forceinline__ float fexp2(float x) { return __builtin_amdgcn_exp2f(x); }
__device__ __forceinline__ float fexp(float x)  { return __builtin_amdgcn_exp2f(x * LOG2E); }
__device__ __forceinline__ float frcp(float x)  { return __builtin_amdgcn_rcpf(x); }
__device__ __forceinline__ float silu_f(float x) {
    return x * frcp(1.f + fexp2(-x * LOG2E));
}
__device__ __forceinline__ void gl_lds(const unsigned short* g, unsigned short* l) {
    __builtin_amdgcn_global_load_lds(
        (__attribute__((address_space(1))) const void*)g,
        (__attribute__((address_space(3))) void*)l, 16, 0, 0);
}

// dims
#define BSZ   2
#define LSEQ  2048
#define DMODEL 1024
#define DI    2048
#define DS    16
#define NCH   64        // chunks
#define CL    32        // steps per chunk (LSEQ/NCH)

// ---------- f32 -> bf16 weight conversion (4 concatenated segments) ----------
#define WI_N   4194304          // 2*DI*DMODEL
#define WXP_N  196608           // 96*DI
#define WDT_N  131072           // DI*64
#define WOUT_N 2097152          // DMODEL*DI
#define WSEG1  (WI_N)
#define WSEG2  (WI_N + WXP_N)
#define WSEG3  (WI_N + WXP_N + WDT_N)
#define WTOT   (WI_N + WXP_N + WDT_N + WOUT_N)   // 6,619,136

__global__ __launch_bounds__(256) void cvt_weights(
    const float* __restrict__ w0, const float* __restrict__ w1,
    const float* __restrict__ w2, const float* __restrict__ w3,
    unsigned short* __restrict__ dst)
{
    const size_t e0 = ((size_t)blockIdx.x * 256 + threadIdx.x) * 8;
    if (e0 >= WTOT) return;
    const float* src;
    size_t off;
    if      (e0 < WSEG1) { src = w0; off = e0; }
    else if (e0 < WSEG2) { src = w1; off = e0 - WSEG1; }
    else if (e0 < WSEG3) { src = w2; off = e0 - WSEG2; }
    else                 { src = w3; off = e0 - WSEG3; }
    float4 a = *(const float4*)(src + off);
    float4 b = *(const float4*)(src + off + 4);
    ushort4 lo, hi;
    lo.x = f2bf(a.x); lo.y = f2bf(a.y); lo.z = f2bf(a.z); lo.w = f2bf(a.w);
    hi.x = f2bf(b.x); hi.y = f2bf(b.y); hi.z = f2bf(b.z); hi.w = f2bf(b.w);
    *(ushort4*)(dst + e0) = lo;
    *(ushort4*)(dst + e0 + 4) = hi;
}

// ---------- LayerNorm (f32 in -> bf16 out) ----------
__global__ __launch_bounds__(256) void ln_kernel(
    const float* __restrict__ x,
    const float* __restrict__ g,
    const float* __restrict__ b,
    unsigned short* __restrict__ xn)
{
    const int row = blockIdx.x;
    const int tid = threadIdx.x;
    const int lane = tid & 63, wv = tid >> 6;
    const float* xp = x + (size_t)row * DMODEL;

    float4 v = ((const float4*)xp)[tid];
    float s = v.x + v.y + v.z + v.w;
    float q = v.x*v.x + v.y*v.y + v.z*v.z + v.w*v.w;
    #pragma unroll
    for (int o = 32; o > 0; o >>= 1) {
        s += __shfl_down(s, o);
        q += __shfl_down(q, o);
    }
    __shared__ float ss[4], sq[4];
    if (lane == 0) { ss[wv] = s; sq[wv] = q; }
    __syncthreads();
    s = ss[0] + ss[1] + ss[2] + ss[3];
    q = sq[0] + sq[1] + sq[2] + sq[3];
    const float mu  = s * (1.f / DMODEL);
    const float var = q * (1.f / DMODEL) - mu * mu;
    const float rs  = rsqrtf(var + 1e-5f);

    float4 gv = ((const float4*)g)[tid];
    float4 bv = ((const float4*)b)[tid];
    ushort4 o;
    o.x = f2bf((v.x - mu) * rs * gv.x + bv.x);
    o.y = f2bf((v.y - mu) * rs * gv.y + bv.y);
    o.z = f2bf((v.z - mu) * rs * gv.z + bv.z);
    o.w = f2bf((v.w - mu) * rs * gv.w + bv.w);
    ((ushort4*)(xn + (size_t)row * DMODEL))[tid] = o;
}

// ---------- 256x256 phase-interleaved pipelined GEMM (8 waves) --------------
// EPI 0: bf16 out via LDS-staged coalesced epilogue (16B/lane, 64B segments)
// EPI 3: f32 out + residual add
template<int EPI, int LOGM>
__global__ __launch_bounds__(512, 2) void gemm_pipe256(
    const unsigned short* __restrict__ A,
    const unsigned short* __restrict__ Bw,
    void* __restrict__ Cout,
    const void* __restrict__ aux0,
    int K, int ldc)
{
    __shared__ unsigned short As[2][256 * 64];
    __shared__ unsigned short Bs[2][256 * 64];
    const int tid  = threadIdx.x;
    const int lane = tid & 63;
    const int wid  = tid >> 6;
    const int wm   = (wid >> 2) * 128;   // 2 wave-rows
    const int wn   = (wid & 3) * 64;     // 4 wave-cols

    const int nwg = gridDim.x;
    const int id  = blockIdx.x;
    const int swz = (id & 7) * (nwg >> 3) + (id >> 3);
    const int bx  = swz & ((1 << LOGM) - 1);
    const int by  = swz >> LOGM;
    const size_t am0 = (size_t)bx * 256;
    const size_t bn0 = (size_t)by * 256;

    const int srow  = lane >> 3;                 // 0..7
    const int sslot = (lane & 7) ^ srow;         // pre-swizzled 16B slot
    const unsigned short* gA = A  + (am0 + wid * 8 + srow) * (size_t)K + sslot * 8;
    const unsigned short* gB = Bw + (bn0 + wid * 8 + srow) * (size_t)K + sslot * 8;

    const int NT = K >> 6;

#define STAGE256(buf, ko)                                                      \
    {   _Pragma("unroll")                                                      \
        for (int j = 0; j < 4; ++j)                                            \
            gl_lds(gA + (size_t)(j * 64) * K + (ko), &As[buf][(j * 64 + wid * 8) * 64]); \
        _Pragma("unroll")                                                      \
        for (int j = 0; j < 4; ++j)                                            \
            gl_lds(gB + (size_t)(j * 64) * K + (ko), &Bs[buf][(j * 64 + wid * 8) * 64]); }

    STAGE256(0, 0)
    STAGE256(1, 64)

    f32x4 acc[8][4];
    f32x4 z4 = {0.f, 0.f, 0.f, 0.f};
    #pragma unroll
    for (int i = 0; i < 8; ++i)
        #pragma unroll
        for (int j = 0; j < 4; ++j) acc[i][j] = z4;

    const int lr  = lane & 15;
    const int lq  = lane >> 4;       // 0..3
    const int key = lr & 7;          // swizzle key (row&7)

#define RD_A(dst, q)                                                           \
    _Pragma("unroll")                                                          \
    for (int i = 0; i < 2; ++i)                                                \
        _Pragma("unroll")                                                      \
        for (int ks = 0; ks < 2; ++ks)                                         \
            dst[i][ks] = *(const bf16x8*)&As[cur][(wm + ((q) * 2 + i) * 16 + lr) * 64 \
                                                  + (((ks * 4 + lq) ^ key) * 8)];

#define MFMA_Q(src, q)                                                         \
    _Pragma("unroll")                                                          \
    for (int i = 0; i < 2; ++i)                                                \
        _Pragma("unroll")                                                      \
        for (int fn = 0; fn < 4; ++fn) {                                       \
            acc[(q) * 2 + i][fn] = __builtin_amdgcn_mfma_f32_16x16x32_bf16(    \
                src[i][0], bfv[fn][0], acc[(q) * 2 + i][fn], 0, 0, 0);         \
            acc[(q) * 2 + i][fn] = __builtin_amdgcn_mfma_f32_16x16x32_bf16(    \
                src[i][1], bfv[fn][1], acc[(q) * 2 + i][fn], 0, 0, 0);         }

    for (int t = 0; t < NT; ++t) {
        const int cur = t & 1;
        if (t < NT - 1) asm volatile("s_waitcnt vmcnt(8)" ::: "memory");
        else            asm volatile("s_waitcnt vmcnt(0)" ::: "memory");
        __builtin_amdgcn_s_barrier();
        __builtin_amdgcn_sched_barrier(0);

        bf16x8 bfv[4][2], fA[2][2], fB[2][2];
        #pragma unroll
        for (int fn = 0; fn < 4; ++fn)
            #pragma unroll
            for (int ks = 0; ks < 2; ++ks)
                bfv[fn][ks] = *(const bf16x8*)&Bs[cur][(wn + fn * 16 + lr) * 64
                                                        + (((ks * 4 + lq) ^ key) * 8)];
        RD_A(fA, 0)
        asm volatile("s_waitcnt lgkmcnt(0)" ::: "memory");
        __builtin_amdgcn_sched_barrier(0);

        RD_A(fB, 1)
        __builtin_amdgcn_s_setprio(1);
        MFMA_Q(fA, 0)
        __builtin_amdgcn_s_setprio(0);
        asm volatile("s_waitcnt lgkmcnt(0)" ::: "memory");
        __builtin_amdgcn_sched_barrier(0);

        RD_A(fA, 2)
        __builtin_amdgcn_s_setprio(1);
        MFMA_Q(fB, 1)
        __builtin_amdgcn_s_setprio(0);
        asm volatile("s_waitcnt lgkmcnt(0)" ::: "memory");
        __builtin_amdgcn_sched_barrier(0);

        RD_A(fB, 3)
        __builtin_amdgcn_s_setprio(1);
        MFMA_Q(fA, 2)
        __builtin_amdgcn_s_setprio(0);
        asm volatile("s_waitcnt lgkmcnt(0)" ::: "memory");
        __builtin_amdgcn_sched_barrier(0);

        __builtin_amdgcn_s_barrier();
        if (t + 2 < NT) {
            STAGE256(cur, (size_t)(t + 2) * 64)
        }
        __builtin_amdgcn_s_setprio(1);
        MFMA_Q(fB, 3)
        __builtin_amdgcn_s_setprio(0);
    }
#undef RD_A
#undef MFMA_Q
#undef STAGE256

    // all waves done reading LDS before epilogue reuses As
    asm volatile("s_waitcnt vmcnt(0) lgkmcnt(0)" ::: "memory");
    __builtin_amdgcn_s_barrier();

    const int er = lq * 4;
    const int ec = lr;
    if constexpr (EPI == 0) {
        // LDS-staged coalesced C-write: per-wave [16][88] bf16 region in As
        unsigned short* cw = &As[0][0] + wid * (16 * 88);
        const int rl  = lane >> 2;        // 0..15
        const int c8l = lane & 3;         // 0..3
        unsigned short* cbase = (unsigned short*)Cout;
        #pragma unroll
        for (int fm = 0; fm < 8; ++fm) {
            #pragma unroll
            for (int fn = 0; fn < 4; ++fn)
                #pragma unroll
                for (int r = 0; r < 4; ++r)
                    cw[(er + r) * 88 + fn * 16 + ec] = f2bf(acc[fm][fn][r]);
            #pragma unroll
            for (int u = 0; u < 2; ++u) {
                const int c8 = c8l + 4 * u;
                bf16x8 v = *(const bf16x8*)&cw[rl * 88 + c8 * 8];
                const size_t row = am0 + wm + fm * 16 + rl;
                const size_t col = bn0 + wn + c8 * 8;
                *(bf16x8*)(cbase + row * (size_t)ldc + col) = v;
            }
        }
    } else {
        #pragma unroll
        for (int fm = 0; fm < 8; ++fm) {
            #pragma unroll
            for (int fn = 0; fn < 4; ++fn) {
                const size_t col = bn0 + wn + fn * 16 + ec;
                #pragma unroll
                for (int r = 0; r < 4; ++r) {
                    const size_t row = am0 + wm + fm * 16 + er + r;
                    float t2 = acc[fm][fn][r] + ((const float*)aux0)[row * ldc + col];
                    ((float*)Cout)[row * ldc + col] = t2;
                }
            }
        }
    }
}

// ---------- 128x128 phase-interleaved pipelined GEMM (8 waves) --------------
template<int EPI, int LOGNB>
__global__ __launch_bounds__(512, 2) void gemm_pipe128(
    const unsigned short* __restrict__ A,
    const unsigned short* __restrict__ Bw,
    void* __restrict__ Cout,
    const void* __restrict__ aux0,
    int K, int ldc)
{
    __shared__ unsigned short As[2][128 * 64];
    __shared__ unsigned short Bs[2][128 * 64];
    const int tid  = threadIdx.x;
    const int lane = tid & 63;
    const int wid  = tid >> 6;
    const int wm   = (wid >> 2) * 64;    // 2 wave-rows
    const int wn   = (wid & 3) * 32;     // 4 wave-cols

    const int nwg = gridDim.x;
    const int id  = blockIdx.x;
    const int swz = (id & 7) * (nwg >> 3) + (id >> 3);
    const int bn_i = swz & ((1 << LOGNB) - 1);
    const int bm_i = swz >> LOGNB;
    const size_t am0 = (size_t)bm_i * 128;
    const size_t bn0 = (size_t)bn_i * 128;

    const int srow  = lane >> 3;                 // 0..7
    const int sslot = (lane & 7) ^ srow;         // pre-swizzled 16B slot
    const unsigned short* gA = A  + (am0 + wid * 16 + srow) * (size_t)K + sslot * 8;
    const unsigned short* gB = Bw + (bn0 + wid * 16 + srow) * (size_t)K + sslot * 8;

    const int NT = K >> 6;

#define STAGE128(buf, ko)                                                      \
    {   _Pragma("unroll")                                                      \
        for (int j = 0; j < 2; ++j)                                            \
            gl_lds(gA + (size_t)(j * 8) * K + (ko), &As[buf][(wid * 16 + j * 8) * 64]); \
        _Pragma("unroll")                                                      \
        for (int j = 0; j < 2; ++j)                                            \
            gl_lds(gB + (size_t)(j * 8) * K + (ko), &Bs[buf][(wid * 16 + j * 8) * 64]); }

    STAGE128(0, 0)
    STAGE128(1, 64)

    f32x4 acc[4][2];
    f32x4 z4 = {0.f, 0.f, 0.f, 0.f};
    #pragma unroll
    for (int i = 0; i < 4; ++i) { acc[i][0] = z4; acc[i][1] = z4; }

    const int lr  = lane & 15;
    const int lq  = lane >> 4;       // 0..3
    const int key = lr & 7;          // swizzle key (row&7)

#define RD_A128(dst, h)                                                        \
    _Pragma("unroll")                                                          \
    for (int i = 0; i < 2; ++i)                                                \
        _Pragma("unroll")                                                      \
        for (int ks = 0; ks < 2; ++ks)                                         \
            dst[i][ks] = *(const bf16x8*)&As[cur][(wm + ((h) * 2 + i) * 16 + lr) * 64 \
                                                  + (((ks * 4 + lq) ^ key) * 8)];

#define MFMA_H(src, h)                                                         \
    _Pragma("unroll")                                                          \
    for (int i = 0; i < 2; ++i)                                                \
        _Pragma("unroll")                                                      \
        for (int fn = 0; fn < 2; ++fn) {                                       \
            acc[(h) * 2 + i][fn] = __builtin_amdgcn_mfma_f32_16x16x32_bf16(    \
                src[i][0], bfv[fn][0], acc[(h) * 2 + i][fn], 0, 0, 0);         \
            acc[(h) * 2 + i][fn] = __builtin_amdgcn_mfma_f32_16x16x32_bf16(    \
                src[i][1], bfv[fn][1], acc[(h) * 2 + i][fn], 0, 0, 0);         }

    for (int t = 0; t < NT; ++t) {
        const int cur = t & 1;
        if (t < NT - 1) asm volatile("s_waitcnt vmcnt(4)" ::: "memory");
        else            asm volatile("s_waitcnt vmcnt(0)" ::: "memory");
        __builtin_amdgcn_s_barrier();
        __builtin_amdgcn_sched_barrier(0);

        bf16x8 bfv[2][2], fA[2][2], fB[2][2];
        #pragma unroll
        for (int fn = 0; fn < 2; ++fn)
            #pragma unroll
            for (int ks = 0; ks < 2; ++ks)
                bfv[fn][ks] = *(const bf16x8*)&Bs[cur][(wn + fn * 16 + lr) * 64
                                                        + (((ks * 4 + lq) ^ key) * 8)];
        RD_A128(fA, 0)
        asm volatile("s_waitcnt lgkmcnt(0)" ::: "memory");
        __builtin_amdgcn_sched_barrier(0);

        RD_A128(fB, 1)
        __builtin_amdgcn_s_setprio(1);
        MFMA_H(fA, 0)
        __builtin_amdgcn_s_setprio(0);
        asm volatile("s_waitcnt lgkmcnt(0)" ::: "memory");
        __builtin_amdgcn_sched_barrier(0);

        __builtin_amdgcn_s_barrier();     // release buf[cur]
        if (t + 2 < NT) {
            STAGE128(cur, (size_t)(t + 2) * 64)
        }
        __builtin_amdgcn_s_setprio(1);
        MFMA_H(fB, 1)
        __builtin_amdgcn_s_setprio(0);
    }
#undef RD_A128
#undef MFMA_H
#undef STAGE128

    const int er = lq * 4;
    const int ec = lr;
    #pragma unroll
    for (int fm = 0; fm < 4; ++fm) {
        #pragma unroll
        for (int fn = 0; fn < 2; ++fn) {
            const size_t col = bn0 + wn + fn * 16 + ec;
            #pragma unroll
            for (int r = 0; r < 4; ++r) {
                const size_t row = am0 + wm + fm * 16 + er + r;
                float v = acc[fm][fn][r];
                if constexpr (EPI == 0) {
                    ((unsigned short*)Cout)[row * ldc + col] = f2bf(v);
                } else {
                    float t2 = v + ((const float*)aux0)[row * ldc + col];
                    ((float*)Cout)[row * ldc + col] = t2;
                }
            }
        }
    }
}

// ---------- tiled GEMM, global_load_lds staging (m97 structure) ----------
template<int BM, int BN, int EPI, int LOG_NBXM>
__global__ __launch_bounds__(256) void gemm_lds(
    const unsigned short* __restrict__ A,
    const unsigned short* __restrict__ Bw,
    void* __restrict__ Cout,
    const void* __restrict__ aux0,
    int K, int ldc)
{
    constexpr int FM = BM / 32;
    constexpr int FN = BN / 32;
    __shared__ unsigned short As[BM * 64];
    __shared__ unsigned short Bs[BN * 64];
    const int tid  = threadIdx.x;
    const int lane = tid & 63;
    const int wv   = tid >> 6;
    const int wm   = (wv >> 1) * (BM / 2);
    const int wn   = (wv & 1)  * (BN / 2);

    const int nwg = gridDim.x;
    const int id  = blockIdx.x;
    const int swz = (id & 7) * (nwg >> 3) + (id >> 3);
    const int bx  = swz & ((1 << LOG_NBXM) - 1);
    const int by  = swz >> LOG_NBXM;

    f32x4 acc[FM][FN];
    f32x4 z4 = {0.f, 0.f, 0.f, 0.f};
    #pragma unroll
    for (int i = 0; i < FM; ++i)
        #pragma unroll
        for (int j = 0; j < FN; ++j) acc[i][j] = z4;

    const size_t am0 = (size_t)bx * BM;
    const size_t bn0 = (size_t)by * BN;
    const int srow  = lane >> 3;          // 0..7
    const int scol  = (lane & 7) * 8;     // 0..56

    for (int k0 = 0; k0 < K; k0 += 64) {
        __syncthreads();
        #pragma unroll
        for (int i = 0; i < BM / 32; ++i) {
            const int rb = (wv * (BM / 32) + i) * 8;
            gl_lds(&A[(am0 + rb + srow) * (size_t)K + k0 + scol], &As[rb * 64]);
        }
        #pragma unroll
        for (int i = 0; i < BN / 32; ++i) {
            const int rb = (wv * (BN / 32) + i) * 8;
            gl_lds(&Bw[(bn0 + rb + srow) * (size_t)K + k0 + scol], &Bs[rb * 64]);
        }
        __syncthreads();
        const int lr = lane & 15, lk = (lane >> 4) * 8;
        #pragma unroll
        for (int ks = 0; ks < 2; ++ks) {
            bf16x8 af[FM], bfv[FN];
            #pragma unroll
            for (int fm = 0; fm < FM; ++fm)
                af[fm] = *(const bf16x8*)&As[(wm + fm * 16 + lr) * 64 + ks * 32 + lk];
            #pragma unroll
            for (int fn = 0; fn < FN; ++fn)
                bfv[fn] = *(const bf16x8*)&Bs[(wn + fn * 16 + lr) * 64 + ks * 32 + lk];
            #pragma unroll
            for (int fm = 0; fm < FM; ++fm)
                #pragma unroll
                for (int fn = 0; fn < FN; ++fn)
                    acc[fm][fn] = __builtin_amdgcn_mfma_f32_16x16x32_bf16(
                        af[fm], bfv[fn], acc[fm][fn], 0, 0, 0);
        }
    }

    const int er = (lane >> 4) * 4;
    const int ec = lane & 15;
    #pragma unroll
    for (int fm = 0; fm < FM; ++fm) {
        #pragma unroll
        for (int fn = 0; fn < FN; ++fn) {
            const size_t col = bn0 + wn + fn * 16 + ec;
            #pragma unroll
            for (int r = 0; r < 4; ++r) {
                const size_t row = am0 + wm + fm * 16 + er + r;
                float v = acc[fm][fn][r];
                if constexpr (EPI == 0) {
                    ((unsigned short*)Cout)[row * ldc + col] = f2bf(v);
                } else if constexpr (EPI == 2) {
                    float t = v + ((const float*)aux0)[col];
                    float e = fexp2(t * LOG2E);
                    float sp = 0.69314718056f * __builtin_amdgcn_logf(1.f + e);
                    if (t > 20.f) sp = t;
                    ((unsigned short*)Cout)[row * ldc + col] = f2bf(sp);
                } else {
                    float t = v + ((const float*)aux0)[row * ldc + col];
                    ((float*)Cout)[row * ldc + col] = t;
                }
            }
        }
    }
}

// ---------- GEMM4 split-K ----------
__global__ __launch_bounds__(256) void gemm4_splitk(
    const unsigned short* __restrict__ A,    // (4096, 2048) bf16
    const unsigned short* __restrict__ Bw,   // (96, 2048) bf16
    float* __restrict__ Cpart)               // (8, 4096, 96) f32
{
    constexpr int LDP = 72;
    __shared__ unsigned short As[64 * LDP];
    __shared__ unsigned short Bs[96 * LDP];
    const int tid  = threadIdx.x;
    const int lane = tid & 63;
    const int wv   = tid >> 6;
    const int wm   = (wv >> 1) * 32;
    const int wn   = (wv & 1)  * 48;

    f32x4 acc[2][3];
    f32x4 z4 = {0.f, 0.f, 0.f, 0.f};
    #pragma unroll
    for (int i = 0; i < 2; ++i)
        #pragma unroll
        for (int j = 0; j < 3; ++j) acc[i][j] = z4;

    const size_t am0 = (size_t)blockIdx.x * 64;
    const int kz = blockIdx.y;
    const int kbeg = kz * 256;
    const int r0 = tid >> 3;
    const int c0 = (tid & 7) * 8;

    for (int k0 = kbeg; k0 < kbeg + 256; k0 += 64) {
        __syncthreads();
        #pragma unroll
        for (int p = 0; p < 2; ++p) {
            int r = r0 + p * 32;
            *(uint4*)&As[r * LDP + c0] = *(const uint4*)&A[(am0 + r) * (size_t)2048 + k0 + c0];
        }
        #pragma unroll
        for (int p = 0; p < 3; ++p) {
            int r = r0 + p * 32;
            *(uint4*)&Bs[r * LDP + c0] = *(const uint4*)&Bw[(size_t)r * 2048 + k0 + c0];
        }
        __syncthreads();
        const int lr = lane & 15, lk = (lane >> 4) * 8;
        #pragma unroll
        for (int ks = 0; ks < 2; ++ks) {
            bf16x8 af[2], bfv[3];
            #pragma unroll
            for (int fm = 0; fm < 2; ++fm)
                af[fm] = *(const bf16x8*)&As[(wm + fm * 16 + lr) * LDP + ks * 32 + lk];
            #pragma unroll
            for (int fn = 0; fn < 3; ++fn)
                bfv[fn] = *(const bf16x8*)&Bs[(wn + fn * 16 + lr) * LDP + ks * 32 + lk];
            #pragma unroll
            for (int fm = 0; fm < 2; ++fm)
                #pragma unroll
                for (int fn = 0; fn < 3; ++fn)
                    acc[fm][fn] = __builtin_amdgcn_mfma_f32_16x16x32_bf16(
                        af[fm], bfv[fn], acc[fm][fn], 0, 0, 0);
        }
    }

    const int er = (lane >> 4) * 4;
    const int ec = lane & 15;
    float* out = Cpart + (size_t)kz * 4096 * 96;
    #pragma unroll
    for (int fm = 0; fm < 2; ++fm) {
        #pragma unroll
        for (int fn = 0; fn < 3; ++fn) {
            const int col = wn + fn * 16 + ec;
            #pragma unroll
            for (int r = 0; r < 4; ++r) {
                const size_t row = am0 + wm + fm * 16 + er + r;
                out[row * 96 + col] = acc[fm][fn][r];
            }
        }
    }
}

// ---------- reduce split-K partials -> x_dbl f32 + dtlow bf16 ----------
__global__ __launch_bounds__(256) void reduce_xdbl(
    const float* __restrict__ Cpart,     // (8, 4096, 96)
    float* __restrict__ x_dbl,           // (4096, 96)
    unsigned short* __restrict__ dtlow)  // (4096, 64) bf16
{
    const int e = blockIdx.x * 256 + threadIdx.x;   // < 393216
    float s = 0.f;
    #pragma unroll
    for (int kz = 0; kz < 8; ++kz) s += Cpart[(size_t)kz * 393216 + e];
    x_dbl[e] = s;
    const int row = e / 96, col = e - row * 96;
    if (col < 64) dtlow[row * 64 + col] = f2bf(s);
}

// ---------- causal depthwise conv (window 4) + bias + SiLU ----------
__global__ __launch_bounds__(256) void conv_silu(
    const unsigned short* __restrict__ xz,     // (B*L, 2*DI) bf16, u = cols [0,DI)
    const float* __restrict__ convw,           // (DI,4) f32
    const float* __restrict__ convb,           // (DI,) f32
    unsigned short* __restrict__ u_c)          // (B*L, DI) bf16
{
    const size_t i = (size_t)blockIdx.x * 256 + threadIdx.x;
    if (i >= (size_t)BSZ * LSEQ * DI) return;
    const int d = (int)(i & (DI - 1));
    const size_t bl = i >> 11;            // b*L + l
    const int l = (int)(bl & (LSEQ - 1));
    const int b = (int)(bl >> 11);

    float4 wv = *(const float4*)&convw[d * 4];
    float acc = convb[d];
    const size_t rowbase = (size_t)(b * LSEQ) * (2 * DI) + d;
    if (l >= 3) acc += bfl(xz[rowbase + (size_t)(l - 3) * (2 * DI)]) * wv.x;
    if (l >= 2) acc += bfl(xz[rowbase + (size_t)(l - 2) * (2 * DI)]) * wv.y;
    if (l >= 1) acc += bfl(xz[rowbase + (size_t)(l - 1) * (2 * DI)]) * wv.z;
    acc += bfl(xz[rowbase + (size_t)l * (2 * DI)]) * wv.w;
    u_c[i] = f2bf(silu_f(acc));
}

// ---------- A-row load: An2[n] = -exp(A_log[d][n]) * log2(e); fast = S4D ----------
__device__ __forceinline__ bool load_A(const float* __restrict__ A_log, int d, float* An2) {
    bool fast = true;
    #pragma unroll
    for (int i = 0; i < 4; ++i) {
        float4 a = *(const float4*)&A_log[(size_t)d * DS + i * 4];
        float e0 = fexp(a.x), e1 = fexp(a.y), e2 = fexp(a.z), e3 = fexp(a.w);
        fast = fast && fabsf(e0 - (4*i+1)) < 1e-3f * (4*i+1)
                    && fabsf(e1 - (4*i+2)) < 1e-3f * (4*i+2)
                    && fabsf(e2 - (4*i+3)) < 1e-3f * (4*i+3)
                    && fabsf(e3 - (4*i+4)) < 1e-3f * (4*i+4);
        An2[4*i+0] = -e0 * LOG2E; An2[4*i+1] = -e1 * LOG2E;
        An2[4*i+2] = -e2 * LOG2E; An2[4*i+3] = -e3 * LOG2E;
    }
    return fast;
}

// ---------- selective scan, pass 1 ----------
__global__ __launch_bounds__(256) void scan1(
    const unsigned short* __restrict__ dt,  // (B*L, DI) bf16
    const unsigned short* __restrict__ u_c, // (B*L, DI) bf16
    const float* __restrict__ x_dbl,        // (B*L, 96) f32; B = cols 64..79
    const float* __restrict__ A_log,        // (DI,16) f32
    float* __restrict__ chunk_h,            // [b][c][d][16] f32
    float* __restrict__ Ssum)               // [b][c][d] f32
{
    const int d = blockIdx.x * 256 + threadIdx.x;
    const int b = blockIdx.y, c = blockIdx.z;
    const int tid = threadIdx.x;

    __shared__ float sB[CL][DS];
    if (tid < 128) {
        int s = tid >> 2, j = (tid & 3) * 4;
        *(float4*)&sB[s][j] =
            *(const float4*)&x_dbl[(size_t)(b * LSEQ + c * CL + s) * 96 + 64 + j];
    }

    float An2[DS];
    const bool fast = load_A(A_log, d, An2);
    __syncthreads();

    float h[DS];
    #pragma unroll
    for (int n = 0; n < DS; ++n) h[n] = 0.f;
    float S = 0.f;
    const size_t base = (size_t)(b * LSEQ + c * CL) * DI + d;
    if (fast) {
        for (int s = 0; s < CL; ++s) {
            float dtt = bfl(dt[base + (size_t)s * DI]);
            float ut  = bfl(u_c[base + (size_t)s * DI]);
            S += dtt;
            float dtu = dtt * ut;
            float e1 = fexp2(-dtt * LOG2E);   // exp(-dt); dA[n] = e1^(n+1)
            float p = 1.f;
            #pragma unroll
            for (int n = 0; n < DS; ++n) {
                p *= e1;
                h[n] = p * h[n] + dtu * sB[s][n];
            }
        }
    } else {
        for (int s = 0; s < CL; ++s) {
            float dtt = bfl(dt[base + (size_t)s * DI]);
            float ut  = bfl(u_c[base + (size_t)s * DI]);
            S += dtt;
            float dtu = dtt * ut;
            #pragma unroll
            for (int n = 0; n < DS; ++n) {
                float dA = fexp2(dtt * An2[n]);
                h[n] = dA * h[n] + dtu * sB[s][n];
            }
        }
    }
    const size_t co = ((size_t)((b * NCH + c) * DI) + d) * DS;
    #pragma unroll
    for (int n = 0; n < DS; ++n) chunk_h[co + n] = h[n];
    Ssum[(size_t)(b * NCH + c) * DI + d] = S;
}

// ---------- scan pass 2 ----------
__global__ __launch_bounds__(256) void scan2(
    float* __restrict__ chunk_h,
    const float* __restrict__ Ssum,
    const float* __restrict__ A_log)
{
    const int gid = blockIdx.x * 256 + threadIdx.x;   // (b,d,n)
    const int b = gid >> 15;
    const int rem = gid & 32767;
    const int d = rem >> 4;
    const int n = rem & 15;
    const float A2 = -fexp(A_log[(size_t)d * DS + n]) * LOG2E;
    float H = 0.f;
    for (int c = 0; c < NCH; ++c) {
        const size_t idx = ((size_t)((b * NCH + c) * DI) + d) * DS + n;
        float hl = chunk_h[idx];
        float S  = Ssum[(size_t)(b * NCH + c) * DI + d];
        chunk_h[idx] = H;                 // start state for chunk c
        H = fexp2(A2 * S) * H + hl;
    }
}

// ---------- scan pass 3 ----------
__global__ __launch_bounds__(256) void scan3(
    const unsigned short* __restrict__ dt,
    const unsigned short* __restrict__ u_c,
    const float* __restrict__ x_dbl,          // B = 64..79, C = 80..95
    const float* __restrict__ A_log,
    const float* __restrict__ Hstart,
    const float* __restrict__ Dvec,           // (DI,) f32
    const unsigned short* __restrict__ xz,    // z = cols [DI, 2*DI) bf16
    unsigned short* __restrict__ yb)          // (B*L, DI) bf16
{
    const int d = blockIdx.x * 256 + threadIdx.x;
    const int b = blockIdx.y, c = blockIdx.z;
    const int tid = threadIdx.x;

    __shared__ float sBC[CL][32];
    {
        int s = tid >> 3, j = (tid & 7) * 4;
        *(float4*)&sBC[s][j] =
            *(const float4*)&x_dbl[(size_t)(b * LSEQ + c * CL + s) * 96 + 64 + j];
    }

    float An2[DS];
    const bool fast = load_A(A_log, d, An2);
    const float Dd = Dvec[d];
    float h[DS];
    const size_t co = ((size_t)((b * NCH + c) * DI) + d) * DS;
    #pragma unroll
    for (int n = 0; n < DS; ++n) h[n] = Hstart[co + n];
    __syncthreads();

    const size_t base  = (size_t)(b * LSEQ + c * CL) * DI + d;
    const size_t zbase = (size_t)(b * LSEQ + c * CL) * (2 * DI) + DI + d;
    if (fast) {
        for (int s = 0; s < CL; ++s) {
            float dtt = bfl(dt[base + (size_t)s * DI]);
            float ut  = bfl(u_c[base + (size_t)s * DI]);
            float dtu = dtt * ut;
            float e1 = fexp2(-dtt * LOG2E);
            float p = 1.f;
            float a0 = 0.f, a1 = 0.f;
            #pragma unroll
            for (int n = 0; n < DS; ++n) {
                p *= e1;
                h[n] = p * h[n] + dtu * sBC[s][n];
                if (n & 1) a1 += h[n] * sBC[s][16 + n];
                else       a0 += h[n] * sBC[s][16 + n];
            }
            float y = a0 + a1 + Dd * ut;
            float z = bfl(xz[zbase + (size_t)s * (2 * DI)]);
            yb[base + (size_t)s * DI] = f2bf(y * silu_f(z));
        }
    } else {
        for (int s = 0; s < CL; ++s) {
            float dtt = bfl(dt[base + (size_t)s * DI]);
            float ut  = bfl(u_c[base + (size_t)s * DI]);
            float dtu = dtt * ut;
            float a0 = 0.f, a1 = 0.f;
            #pragma unroll
            for (int n = 0; n < DS; ++n) {
                float dA = fexp2(dtt * An2[n]);
                h[n] = dA * h[n] + dtu * sBC[s][n];
                if (n & 1) a1 += h[n] * sBC[s][16 + n];
                else       a0 += h[n] * sBC[s][16 + n];
            }
            float y = a0 + a1 + Dd * ut;
            float z = bfl(xz[zbase + (size_t)s * (2 * DI)]);
            yb[base + (size_t)s * DI] = f2bf(y * silu_f(z));
        }
    }
}

// ---------- host launcher ----------
extern "C" void kernel_launch(void* const* d_in, const int* in_sizes, int n_in,
                              void* d_out, int out_size, void* d_ws, size_t ws_size,
                              hipStream_t stream) {
    const float* x      = (const float*)d_in[0];
    const float* ln_g   = (const float*)d_in[1];
    const float* ln_b   = (const float*)d_in[2];
    const float* W_in   = (const float*)d_in[3];
    const float* conv_w = (const float*)d_in[4];
    const float* conv_b = (const float*)d_in[5];
    const float* W_xp   = (const float*)d_in[6];
    const float* W_dt   = (const float*)d_in[7];
    const float* b_dt   = (const float*)d_in[8];
    const float* A_log  = (const float*)d_in[9];
    const float* Dv     = (const float*)d_in[10];
    const float* W_out  = (const float*)d_in[11];
    float* out = (float*)d_out;

    char* w = (char*)d_ws;
    unsigned short* xn     = (unsigned short*)(w + 0);           //  8,388,608
    unsigned short* xz     = (unsigned short*)(w + 8388608);     // 33,554,432
    unsigned short* u_c    = (unsigned short*)(w + 41943040);    // 16,777,216
    float*          x_dbl  = (float*)         (w + 58720256);    //  1,572,864
    unsigned short* dtlow  = (unsigned short*)(w + 60293120);    //    524,288
    unsigned short* dtb    = (unsigned short*)(w + 60817408);    // 16,777,216 (bf16)
    float*          chunkh = (float*)         (w + 77594624);    // 16,777,216
    float*          Ssum   = (float*)         (w + 94371840);    //  1,048,576
    unsigned short* yb     = (unsigned short*)(w + 95420416);    // 16,777,216
    unsigned short* wbf    = (unsigned short*)(w + 112197632);   // 13,238,272
    float*          Cpart  = (float*)         (w + 125435904);   // 12,582,912 (end 138,018,816)
    unsigned short* Wi_bf   = wbf;
    unsigned short* Wxp_bf  = wbf + WSEG1;
    unsigned short* Wdt_bf  = wbf + WSEG2;
    unsigned short* Wout_bf = wbf + WSEG3;
    (void)in_sizes; (void)n_in; (void)out_size; (void)ws_size;

    const int MROWS = BSZ * LSEQ;  // 4096

    // 0. weights f32 -> bf16
    cvt_weights<<<(WTOT / 8 + 255) / 256, 256, 0, stream>>>(
        W_in, W_xp, W_dt, W_out, wbf);
    // 1. LayerNorm (f32 -> bf16)
    ln_kernel<<<MROWS, 256, 0, stream>>>(x, ln_g, ln_b, xn);
    // 2. xz = xn @ W_in^T  (4096x1024 @ 1024x4096) -> bf16
    //    256x256 tiles: 16 M-tiles (LOGM=4) x 16 N-tiles = 256 blocks
    //    LDS-staged coalesced epilogue (64B write segments)
    gemm_pipe256<0, 4><<<256, 512, 0, stream>>>(
        xn, Wi_bf, xz, nullptr, DMODEL, 2 * DI);
    // 3. causal conv + SiLU -> bf16
    conv_silu<<<(MROWS * DI) / 256, 256, 0, stream>>>(xz, conv_w, conv_b, u_c);
    // 4. x_dbl = u_c @ W_xp^T  (4096x2048 @ 2048x96), split-K + reduce
    gemm4_splitk<<<dim3(64, 8), 256, 0, stream>>>(u_c, Wxp_bf, Cpart);
    reduce_xdbl<<<(MROWS * 96) / 256, 256, 0, stream>>>(Cpart, x_dbl, dtlow);
    // 5. dt = softplus(dtlow @ W_dt^T + b_dt)  (4096x64 @ 64x2048) -> bf16
    gemm_lds<128, 64, 2, 5><<<1024, 256, 0, stream>>>(
        dtlow, Wdt_bf, dtb, b_dt, 64, DI);
    // 6-8. chunked selective scan (+ D*u, * silu(z)) -> yb bf16
    scan1<<<dim3(DI / 256, BSZ, NCH), 256, 0, stream>>>(
        dtb, u_c, x_dbl, A_log, chunkh, Ssum);
    scan2<<<(BSZ * DI * DS) / 256, 256, 0, stream>>>(chunkh, Ssum, A_log);
    scan3<<<dim3(DI / 256, BSZ, NCH), 256, 0, stream>>>(
        dtb, u_c, x_dbl, A_log, chunkh, Dv, xz, yb);
    // 9. out = yb @ W_out^T + x  (4096x2048 @ 2048x1024) -> f32
    //    128x128 pipelined: 8 N-tiles (LOGNB=3) x 32 M-tiles = 256 blocks
    gemm_pipe128<3, 3><<<256, 512, 0, stream>>>(
        yb, Wout_bf, out, x, DI, DMODEL);
}